// Round 2
// baseline (378.782 us; speedup 1.0000x reference)
//
#include <hip/hip_runtime.h>

// ResamplerLayer: trilinear resample with ZERO-boundary (replicate-clamp) semantics.
// d_in[0] = inputs        [B=2,128,128,128,C=4] f32
// d_in[1] = sample_coords [B=2,96,96,96,3]      f32  (order: D,H,W)
// d_out   = [B=2,96,96,96,4] f32
//
// Strategy (R2): coords are random-uniform -> the naive gather misses L2
// (448 MB FETCH vs 116 MB compulsory). Bin samples by 8^3-voxel input cell,
// then gather bucket-by-bucket so each block's 8-corner reads hit a ~15 KB
// window that lives in L2/L1.

constexpr int D = 128, H = 128, W = 128;
constexpr int OD = 96, OH = 96, OW = 96;
constexpr int VOX_PER_B = OD * OH * OW;          // 884736
constexpr int NVOX = 2 * VOX_PER_B;              // 1769472

constexpr int NBUCKETS = 8192;                   // 2 * 16*16*16 cells (8^3 voxels each)
constexpr int PAD = 16;                          // u32 stride per counter -> 64 B/counter

// workspace layout (bytes)
constexpr size_t OFF_COUNTS  = 0;                          // 8192*16*4 = 512 KiB
constexpr size_t OFF_CURSORS = 512 * 1024;                 // 512 KiB
constexpr size_t OFF_OFFSETS = 1024 * 1024;                // 8193*4 ≈ 32 KiB
constexpr size_t OFF_RECORDS = 1024 * 1024 + 64 * 1024;    // NVOX*16 = 27 MiB
constexpr size_t WS_REQUIRED = OFF_RECORDS + (size_t)NVOX * 16;

__device__ __forceinline__ float4 f4_fma(float w, float4 a, float4 acc) {
    acc.x = fmaf(w, a.x, acc.x);
    acc.y = fmaf(w, a.y, acc.y);
    acc.z = fmaf(w, a.z, acc.z);
    acc.w = fmaf(w, a.w, acc.w);
    return acc;
}
__device__ __forceinline__ float4 f4_scale(float w, float4 a) {
    return make_float4(w * a.x, w * a.y, w * a.z, w * a.w);
}

__device__ __forceinline__ int bucket_of(float cz, float cy, float cx, int b) {
    int z0 = min(max((int)floorf(cz), 0), D - 1);
    int y0 = min(max((int)floorf(cy), 0), H - 1);
    int x0 = min(max((int)floorf(cx), 0), W - 1);
    // linear = ((b*16 + zc)*16 + yc)*16 + xc  -> contiguous z-slabs per XCD
    return (((b << 4) | (z0 >> 3)) << 8) | ((y0 >> 3) << 4) | (x0 >> 3);
}

// trilinear sample + blend, identical math to the R1 kernel
__device__ __forceinline__ float4 trilinear(const float* __restrict__ inp,
                                            float cz, float cy, float cx, int b) {
    const int fz = (int)floorf(cz);
    const int fy = (int)floorf(cy);
    const int fx = (int)floorf(cx);

    const int z1 = min(max(fz + 1, 0), D - 1);
    const int y1 = min(max(fy + 1, 0), H - 1);
    const int x1 = min(max(fx + 1, 0), W - 1);
    const int z0 = min(max(fz, 0), D - 1);
    const int y0 = min(max(fy, 0), H - 1);
    const int x0 = min(max(fx, 0), W - 1);

    const float wz0 = (float)z1 - cz, wz1 = cz - (float)z0;
    const float wy0 = (float)y1 - cy, wy1 = cy - (float)y0;
    const float wx0 = (float)x1 - cx, wx1 = cx - (float)x0;

    const float4* bp = (const float4*)inp + ((size_t)b << 21);
    const int z0o = z0 << 14, z1o = z1 << 14;
    const int y0o = y0 << 7,  y1o = y1 << 7;

    const float4 s000 = bp[z0o | y0o | x0];
    const float4 s001 = bp[z0o | y0o | x1];
    const float4 s010 = bp[z0o | y1o | x0];
    const float4 s011 = bp[z0o | y1o | x1];
    const float4 s100 = bp[z1o | y0o | x0];
    const float4 s101 = bp[z1o | y0o | x1];
    const float4 s110 = bp[z1o | y1o | x0];
    const float4 s111 = bp[z1o | y1o | x1];

    float4 c00 = f4_fma(wx1, s001, f4_scale(wx0, s000));
    float4 c01 = f4_fma(wx1, s011, f4_scale(wx0, s010));
    float4 c10 = f4_fma(wx1, s101, f4_scale(wx0, s100));
    float4 c11 = f4_fma(wx1, s111, f4_scale(wx0, s110));

    float4 c0 = f4_fma(wy1, c01, f4_scale(wy0, c00));
    float4 c1 = f4_fma(wy1, c11, f4_scale(wy0, c10));

    return f4_fma(wz1, c1, f4_scale(wz0, c0));
}

// ---- pass 1: histogram ------------------------------------------------------
__global__ __launch_bounds__(256) void hist_kernel(const float* __restrict__ coords,
                                                   unsigned* __restrict__ counts) {
    int idx = blockIdx.x * 256 + threadIdx.x;
    if (idx >= NVOX) return;
    const float cz = coords[idx * 3 + 0];
    const float cy = coords[idx * 3 + 1];
    const float cx = coords[idx * 3 + 2];
    const int b = (idx >= VOX_PER_B) ? 1 : 0;
    atomicAdd(&counts[bucket_of(cz, cy, cx, b) * PAD], 1u);
}

// ---- pass 2: exclusive scan (single block) ---------------------------------
__global__ __launch_bounds__(1024) void scan_kernel(const unsigned* __restrict__ counts,
                                                    unsigned* __restrict__ cursors,
                                                    unsigned* __restrict__ offsets) {
    const int tid = threadIdx.x;
    unsigned v[8];
    unsigned sum = 0;
#pragma unroll
    for (int j = 0; j < 8; j++) { v[j] = counts[(tid * 8 + j) * PAD]; sum += v[j]; }

    __shared__ unsigned s[1024];
    s[tid] = sum;
    __syncthreads();
    for (int off = 1; off < 1024; off <<= 1) {
        unsigned t = (tid >= off) ? s[tid - off] : 0u;
        __syncthreads();
        s[tid] += t;
        __syncthreads();
    }
    unsigned run = s[tid] - sum;  // exclusive prefix of this thread's 8 bins
#pragma unroll
    for (int j = 0; j < 8; j++) {
        int bkt = tid * 8 + j;
        offsets[bkt] = run;
        cursors[bkt * PAD] = run;
        run += v[j];
    }
    if (tid == 1023) offsets[NBUCKETS] = run;   // == NVOX
}

// ---- pass 3: scatter records into bucket order ------------------------------
__global__ __launch_bounds__(256) void scatter_kernel(const float* __restrict__ coords,
                                                      unsigned* __restrict__ cursors,
                                                      float4* __restrict__ records) {
    int idx = blockIdx.x * 256 + threadIdx.x;
    if (idx >= NVOX) return;
    const float cz = coords[idx * 3 + 0];
    const float cy = coords[idx * 3 + 1];
    const float cx = coords[idx * 3 + 2];
    const int b = (idx >= VOX_PER_B) ? 1 : 0;
    const int bk = bucket_of(cz, cy, cx, b);
    const unsigned slot = atomicAdd(&cursors[bk * PAD], 1u);
    records[slot] = make_float4(cz, cy, cx, __uint_as_float((unsigned)idx));
}

// ---- pass 4: bucket-local gather -------------------------------------------
__global__ __launch_bounds__(256) void gather_kernel(const float* __restrict__ inp,
                                                     const float4* __restrict__ records,
                                                     const unsigned* __restrict__ offsets,
                                                     float4* __restrict__ out) {
    // blockIdx&7 -> XCD (round-robin heuristic); blockIdx>>3 walks cells in
    // (b,z,y,x) order within each XCD's contiguous z-slab range.
    const int bucket = (blockIdx.x & 7) * (NBUCKETS / 8) + (blockIdx.x >> 3);
    const unsigned start = offsets[bucket];
    const unsigned end   = offsets[bucket + 1];
    for (unsigned i = start + threadIdx.x; i < end; i += 256) {
        const float4 r = records[i];
        const unsigned idx = __float_as_uint(r.w);
        const int b = (idx >= (unsigned)VOX_PER_B) ? 1 : 0;
        out[idx] = trilinear(inp, r.x, r.y, r.z, b);
    }
}

// ---- fallback: direct (R1) kernel, used if ws too small ---------------------
__global__ __launch_bounds__(256) void direct_kernel(const float* __restrict__ inp,
                                                     const float* __restrict__ coords,
                                                     float4* __restrict__ out) {
    int idx = blockIdx.x * 256 + threadIdx.x;
    if (idx >= NVOX) return;
    const float cz = coords[idx * 3 + 0];
    const float cy = coords[idx * 3 + 1];
    const float cx = coords[idx * 3 + 2];
    const int b = (idx >= VOX_PER_B) ? 1 : 0;
    out[idx] = trilinear(inp, cz, cy, cx, b);
}

extern "C" void kernel_launch(void* const* d_in, const int* in_sizes, int n_in,
                              void* d_out, int out_size, void* d_ws, size_t ws_size,
                              hipStream_t stream) {
    const float* inp    = (const float*)d_in[0];
    const float* coords = (const float*)d_in[1];
    float4* out = (float4*)d_out;

    const int blocks = (NVOX + 255) / 256;   // 6912

    if (ws_size < WS_REQUIRED) {
        direct_kernel<<<blocks, 256, 0, stream>>>(inp, coords, out);
        return;
    }

    char* ws = (char*)d_ws;
    unsigned* counts  = (unsigned*)(ws + OFF_COUNTS);
    unsigned* cursors = (unsigned*)(ws + OFF_CURSORS);
    unsigned* offsets = (unsigned*)(ws + OFF_OFFSETS);
    float4*   records = (float4*)(ws + OFF_RECORDS);

    hipMemsetAsync(counts, 0, NBUCKETS * PAD * sizeof(unsigned), stream);
    hist_kernel<<<blocks, 256, 0, stream>>>(coords, counts);
    scan_kernel<<<1, 1024, 0, stream>>>(counts, cursors, offsets);
    scatter_kernel<<<blocks, 256, 0, stream>>>(coords, cursors, records);
    gather_kernel<<<NBUCKETS, 256, 0, stream>>>(inp, records, offsets, out);
}

// Round 3
// 296.093 us; speedup vs baseline: 1.2793x; 1.2793x over previous
//
#include <hip/hip_runtime.h>

// ResamplerLayer: trilinear resample with ZERO-boundary (replicate-clamp) semantics.
// d_in[0] = inputs        [B=2,128,128,128,C=4] f32
// d_in[1] = sample_coords [B=2,96,96,96,3]      f32  (order: D,H,W)
// d_out   = [B=2,96,96,96,4] f32
//
// R3: counting-sort samples into 32 z-slab buckets (2 batches x 16 slabs of 8
// planes; slab+halo = 2.4 MB -> fits 4 MB XCD L2), with deterministic slots
// (no global atomics) and LDS-staged near-coalesced record writes. Gather is
// XCD-pinned, walking slabs sequentially so corner reads hit L2.

constexpr int D = 128, H = 128, W = 128;
constexpr int OD = 96, OH = 96, OW = 96;
constexpr int VOX_PER_B = OD * OH * OW;          // 884736
constexpr int NVOX = 2 * VOX_PER_B;              // 1769472 == 6912*256 exactly
constexpr int NBLK = NVOX / 256;                 // 6912
constexpr int NBUCKETS = 32;                     // 2 batches x 16 z-slabs
constexpr int SCAN_THREADS = 1024;
constexpr int SCAN_CHUNK = NBUCKETS * NBLK / SCAN_THREADS;   // 216 exact
constexpr int GB_PER_XCD = 256;                  // gather blocks per XCD
constexpr int GATHER_GRID = 8 * GB_PER_XCD;      // 2048

// workspace layout (bytes)
constexpr size_t OFF_COUNTS  = 0;                              // u32[32][6912] = 884736 B
constexpr size_t OFF_BOFF    = 1024 * 1024;                    // u32[33]
constexpr size_t OFF_RECORDS = 1024 * 1024 + 4096;
constexpr size_t WS_REQUIRED = OFF_RECORDS + (size_t)NVOX * 16;

__device__ __forceinline__ int bucket_of(float cz, int b) {
    int z0 = min(max((int)floorf(cz), 0), D - 1);
    return (b << 4) | (z0 >> 3);
}

__device__ __forceinline__ float4 f4_fma(float w, float4 a, float4 acc) {
    acc.x = fmaf(w, a.x, acc.x);
    acc.y = fmaf(w, a.y, acc.y);
    acc.z = fmaf(w, a.z, acc.z);
    acc.w = fmaf(w, a.w, acc.w);
    return acc;
}
__device__ __forceinline__ float4 f4_scale(float w, float4 a) {
    return make_float4(w * a.x, w * a.y, w * a.z, w * a.w);
}

__device__ __forceinline__ float4 trilinear(const float* __restrict__ inp,
                                            float cz, float cy, float cx, int b) {
    const int fz = (int)floorf(cz);
    const int fy = (int)floorf(cy);
    const int fx = (int)floorf(cx);

    const int z1 = min(max(fz + 1, 0), D - 1);
    const int y1 = min(max(fy + 1, 0), H - 1);
    const int x1 = min(max(fx + 1, 0), W - 1);
    const int z0 = min(max(fz, 0), D - 1);
    const int y0 = min(max(fy, 0), H - 1);
    const int x0 = min(max(fx, 0), W - 1);

    const float wz0 = (float)z1 - cz, wz1 = cz - (float)z0;
    const float wy0 = (float)y1 - cy, wy1 = cy - (float)y0;
    const float wx0 = (float)x1 - cx, wx1 = cx - (float)x0;

    const float4* bp = (const float4*)inp + ((size_t)b << 21);
    const int z0o = z0 << 14, z1o = z1 << 14;
    const int y0o = y0 << 7,  y1o = y1 << 7;

    const float4 s000 = bp[z0o | y0o | x0];
    const float4 s001 = bp[z0o | y0o | x1];
    const float4 s010 = bp[z0o | y1o | x0];
    const float4 s011 = bp[z0o | y1o | x1];
    const float4 s100 = bp[z1o | y0o | x0];
    const float4 s101 = bp[z1o | y0o | x1];
    const float4 s110 = bp[z1o | y1o | x0];
    const float4 s111 = bp[z1o | y1o | x1];

    float4 c00 = f4_fma(wx1, s001, f4_scale(wx0, s000));
    float4 c01 = f4_fma(wx1, s011, f4_scale(wx0, s010));
    float4 c10 = f4_fma(wx1, s101, f4_scale(wx0, s100));
    float4 c11 = f4_fma(wx1, s111, f4_scale(wx0, s110));

    float4 c0 = f4_fma(wy1, c01, f4_scale(wy0, c00));
    float4 c1 = f4_fma(wy1, c11, f4_scale(wy0, c10));

    return f4_fma(wz1, c1, f4_scale(wz0, c0));
}

// ---- pass 1: per-block histogram (LDS bins, no global atomics) -------------
__global__ __launch_bounds__(256) void hist_kernel(const float* __restrict__ coords,
                                                   unsigned* __restrict__ counts) {
    __shared__ unsigned cnt[NBUCKETS];
    const int t = threadIdx.x;
    if (t < NBUCKETS) cnt[t] = 0;
    __syncthreads();
    const int idx = blockIdx.x * 256 + t;           // grid covers NVOX exactly
    const float cz = coords[idx * 3 + 0];
    const int b = (idx >= VOX_PER_B) ? 1 : 0;
    atomicAdd(&cnt[bucket_of(cz, b)], 1u);
    __syncthreads();
    if (t < NBUCKETS) counts[t * NBLK + blockIdx.x] = cnt[t];   // bucket-major
}

// ---- pass 2: exclusive scan of the 32x6912 matrix (in place) ----------------
__global__ __launch_bounds__(SCAN_THREADS) void scan_kernel(unsigned* __restrict__ counts,
                                                            unsigned* __restrict__ boff) {
    const int t = threadIdx.x;
    const int base = t * SCAN_CHUNK;
    unsigned sum = 0;
    for (int j = 0; j < SCAN_CHUNK; j++) sum += counts[base + j];

    __shared__ unsigned s[SCAN_THREADS];
    s[t] = sum;
    __syncthreads();
    for (int off = 1; off < SCAN_THREADS; off <<= 1) {
        unsigned v = (t >= off) ? s[t - off] : 0u;
        __syncthreads();
        s[t] += v;
        __syncthreads();
    }
    unsigned run = s[t] - sum;                       // global exclusive prefix at element base
    if ((t & 31) == 0) boff[t >> 5] = run;           // element 32k*216 == k*6912 -> bucket k start
    if (t == 0) boff[NBUCKETS] = NVOX;
    for (int j = 0; j < SCAN_CHUNK; j++) {
        unsigned c = counts[base + j];
        counts[base + j] = run;                      // becomes base[bucket][block]
        run += c;
    }
}

// ---- pass 3: deterministic LDS-staged scatter -------------------------------
__global__ __launch_bounds__(256) void scatter_kernel(const float* __restrict__ coords,
                                                      const unsigned* __restrict__ base,
                                                      float4* __restrict__ records) {
    __shared__ unsigned cnt[NBUCKETS], loff[NBUCKETS], gbase[NBUCKETS];
    __shared__ float4 rec[256];
    __shared__ unsigned char rbk[256];
    const int t = threadIdx.x;
    const int blk = blockIdx.x;
    if (t < NBUCKETS) { cnt[t] = 0; gbase[t] = base[t * NBLK + blk]; }
    __syncthreads();

    const int idx = blk * 256 + t;
    const float cz = coords[idx * 3 + 0];
    const float cy = coords[idx * 3 + 1];
    const float cx = coords[idx * 3 + 2];
    const int b = (idx >= VOX_PER_B) ? 1 : 0;
    const int k = bucket_of(cz, b);
    const unsigned rank = atomicAdd(&cnt[k], 1u);    // LDS atomic, cheap
    __syncthreads();

    if (t < NBUCKETS) {                              // tiny serial exclusive scan of 32 bins
        unsigned r = 0;
        for (int i = 0; i < t; i++) r += cnt[i];
        loff[t] = r;
    }
    __syncthreads();

    const unsigned slot = loff[k] + rank;            // block-local sorted position
    rec[slot] = make_float4(cz, cy, cx, __uint_as_float((unsigned)idx));
    rbk[slot] = (unsigned char)k;
    __syncthreads();

    const int k2 = rbk[t];                           // write sorted: contiguous per-run dests
    records[gbase[k2] + (t - loff[k2])] = rec[t];
}

// ---- pass 4: XCD-pinned, slab-sequential gather -----------------------------
__global__ __launch_bounds__(256) void gather_kernel(const float* __restrict__ inp,
                                                     const float4* __restrict__ records,
                                                     const unsigned* __restrict__ boff,
                                                     float4* __restrict__ out) {
    const int xcd = blockIdx.x & 7;                  // round-robin XCD heuristic
    const int seq = blockIdx.x >> 3;                 // 0..GB_PER_XCD-1
    for (int j = 0; j < 4; j++) {                    // this XCD's 4 z-slab buckets, in order
        const int bucket = xcd * 4 + j;
        const unsigned s = boff[bucket];
        const unsigned e = boff[bucket + 1];
        const unsigned len = e - s;
        const unsigned chunk = (len + GB_PER_XCD - 1) / GB_PER_XCD;
        const unsigned st = s + seq * chunk;
        const unsigned en = min(st + chunk, e);
        for (unsigned i = st + threadIdx.x; i < en; i += 256) {
            const float4 r = records[i];
            const unsigned idx = __float_as_uint(r.w);
            const int b = (idx >= (unsigned)VOX_PER_B) ? 1 : 0;
            out[idx] = trilinear(inp, r.x, r.y, r.z, b);
        }
    }
}

// ---- fallback: direct (R1) kernel ------------------------------------------
__global__ __launch_bounds__(256) void direct_kernel(const float* __restrict__ inp,
                                                     const float* __restrict__ coords,
                                                     float4* __restrict__ out) {
    const int idx = blockIdx.x * 256 + threadIdx.x;
    if (idx >= NVOX) return;
    const float cz = coords[idx * 3 + 0];
    const float cy = coords[idx * 3 + 1];
    const float cx = coords[idx * 3 + 2];
    const int b = (idx >= VOX_PER_B) ? 1 : 0;
    out[idx] = trilinear(inp, cz, cy, cx, b);
}

extern "C" void kernel_launch(void* const* d_in, const int* in_sizes, int n_in,
                              void* d_out, int out_size, void* d_ws, size_t ws_size,
                              hipStream_t stream) {
    const float* inp    = (const float*)d_in[0];
    const float* coords = (const float*)d_in[1];
    float4* out = (float4*)d_out;

    if (ws_size < WS_REQUIRED) {
        direct_kernel<<<NBLK, 256, 0, stream>>>(inp, coords, out);
        return;
    }

    char* ws = (char*)d_ws;
    unsigned* counts  = (unsigned*)(ws + OFF_COUNTS);
    unsigned* boff    = (unsigned*)(ws + OFF_BOFF);
    float4*   records = (float4*)(ws + OFF_RECORDS);

    hist_kernel   <<<NBLK, 256, 0, stream>>>(coords, counts);
    scan_kernel   <<<1, SCAN_THREADS, 0, stream>>>(counts, boff);
    scatter_kernel<<<NBLK, 256, 0, stream>>>(coords, counts, records);
    gather_kernel <<<GATHER_GRID, 256, 0, stream>>>(inp, records, boff, out);
}

// Round 4
// 174.515 us; speedup vs baseline: 2.1705x; 1.6967x over previous
//
#include <hip/hip_runtime.h>

// ResamplerLayer: trilinear resample, ZERO-boundary (replicate-clamp) semantics.
// d_in[0] = inputs        [B=2,128,128,128,C=4] f32
// d_in[1] = sample_coords [B=2,96,96,96,3]      f32  (order: D,H,W)
// d_out   = [B=2,96,96,96,4] f32
//
// R4: exact counting sort into 1024 bins (2 batches x 16 z-slabs x 32 y-slabs;
// bin tile 8x4x128 voxels + halo = 9x5x128 float4 = 92 KB -> fits LDS).
// Gather stages the tile into LDS once (coalesced), then all 8 corner reads
// per sample are ds_read_b128 (R3 showed L1-miss MSHR latency kills global
// corner reads). Sort passes are parallel + coalesced (R3's 1-block scan and
// R2's random scatter writes were the previous failures).

constexpr int D = 128, H = 128, W = 128;
constexpr int OD = 96, OH = 96, OW = 96;
constexpr int VOX_PER_B = OD * OH * OW;          // 884736
constexpr int NVOX = 2 * VOX_PER_B;              // 1769472 = 216 * 8192 exactly

constexpr int NBINS = 1024;                      // (b,zb,yb): 2*16*32
constexpr int NB1 = 216;                         // hist/scatter blocks
constexpr int SPB = 8192;                        // samples per hist/scatter block
constexpr int GATHER_THREADS = 1024;
constexpr int TILE_ELEMS = 9 * 5 * 128;          // 5760 float4 = 92160 B LDS

// workspace layout (bytes); known available >= 29,425,664 (R2 ran binned path)
constexpr size_t OFF_MATRIX  = 0;                            // u32[216][1024] blk-major
constexpr size_t OFF_NCNT    = (size_t)NB1 * NBINS * 4;      // 884736
constexpr size_t OFF_BASE    = OFF_NCNT + NBINS * 4;         // 888832
constexpr size_t OFF_RECORDS = OFF_BASE + NBINS * 4;         // 892928 (16-aligned)
constexpr size_t WS_REQUIRED = OFF_RECORDS + (size_t)NVOX * 16;  // 29,204,480

__device__ __forceinline__ int bin_of(float cz, float cy, int b) {
    int z0 = min(max((int)floorf(cz), 0), D - 1);
    int y0 = min(max((int)floorf(cy), 0), H - 1);
    return (((b << 4) | (z0 >> 3)) << 5) | (y0 >> 2);
}

__device__ __forceinline__ float4 f4_fma(float w, float4 a, float4 acc) {
    acc.x = fmaf(w, a.x, acc.x);
    acc.y = fmaf(w, a.y, acc.y);
    acc.z = fmaf(w, a.z, acc.z);
    acc.w = fmaf(w, a.w, acc.w);
    return acc;
}
__device__ __forceinline__ float4 f4_scale(float w, float4 a) {
    return make_float4(w * a.x, w * a.y, w * a.z, w * a.w);
}

// ---- pass 1: histogram (LDS bins, coalesced blk-major matrix write) --------
__global__ __launch_bounds__(1024) void hist_kernel(const float* __restrict__ coords,
                                                    unsigned* __restrict__ matrix) {
    __shared__ unsigned cnt[NBINS];
    const int t = threadIdx.x;
    cnt[t] = 0;
    __syncthreads();
    const int s0 = blockIdx.x * SPB;
#pragma unroll
    for (int j = 0; j < 8; j++) {
        const int s = s0 + j * 1024 + t;
        const float cz = coords[s * 3 + 0];
        const float cy = coords[s * 3 + 1];
        const int b = (s >= VOX_PER_B) ? 1 : 0;
        atomicAdd(&cnt[bin_of(cz, cy, b)], 1u);
    }
    __syncthreads();
    matrix[blockIdx.x * NBINS + t] = cnt[t];     // coalesced
}

// ---- pass 2a: per-bin exclusive scan over the 216 blocks --------------------
__global__ __launch_bounds__(256) void scanA_kernel(unsigned* __restrict__ matrix,
                                                    unsigned* __restrict__ ncnt) {
    const int k = blockIdx.x;                    // bin
    const int t = threadIdx.x;
    const unsigned v = (t < NB1) ? matrix[t * NBINS + k] : 0u;
    __shared__ unsigned s[256];
    s[t] = v;
    __syncthreads();
    for (int off = 1; off < 256; off <<= 1) {
        unsigned u = (t >= off) ? s[t - off] : 0u;
        __syncthreads();
        s[t] += u;
        __syncthreads();
    }
    if (t < NB1) matrix[t * NBINS + k] = s[t] - v;   // exclusive prefix
    if (t == 255) ncnt[k] = s[255];                  // bin total
}

// ---- pass 2b: exclusive scan of 1024 bin totals -> bases --------------------
__global__ __launch_bounds__(1024) void scanB_kernel(const unsigned* __restrict__ ncnt,
                                                     unsigned* __restrict__ base) {
    const int t = threadIdx.x;
    const unsigned v = ncnt[t];
    __shared__ unsigned s[NBINS];
    s[t] = v;
    __syncthreads();
    for (int off = 1; off < NBINS; off <<= 1) {
        unsigned u = (t >= off) ? s[t - off] : 0u;
        __syncthreads();
        s[t] += u;
        __syncthreads();
    }
    base[t] = s[t] - v;
}

// ---- pass 3: deterministic LDS-staged scatter (runs of ~8, no global atomics)
__global__ __launch_bounds__(1024) void scatter_kernel(const float* __restrict__ coords,
                                                       const unsigned* __restrict__ matrix,
                                                       const unsigned* __restrict__ base,
                                                       float4* __restrict__ records) {
    __shared__ float4 rec[SPB];                  // 128 KiB
    __shared__ unsigned short binid[SPB];        // 16 KiB
    __shared__ unsigned cnt[NBINS];              // 4 KiB
    __shared__ unsigned pref[NBINS];             // 4 KiB
    __shared__ unsigned gb[NBINS];               // 4 KiB  (total 156 KiB <= 160)
    const int t = threadIdx.x;
    const int blk = blockIdx.x;
    cnt[t] = 0;
    gb[t] = base[t] + matrix[blk * NBINS + t];   // coalesced
    __syncthreads();

    const int s0 = blk * SPB;
    float czr[8], cyr[8], cxr[8];
    unsigned rankr[8];
#pragma unroll
    for (int j = 0; j < 8; j++) {
        const int s = s0 + j * 1024 + t;
        czr[j] = coords[s * 3 + 0];
        cyr[j] = coords[s * 3 + 1];
        cxr[j] = coords[s * 3 + 2];
        const int b = (s >= VOX_PER_B) ? 1 : 0;
        rankr[j] = atomicAdd(&cnt[bin_of(czr[j], cyr[j], b)], 1u);
    }
    __syncthreads();

    // exclusive scan cnt -> pref (Hillis-Steele in pref)
    pref[t] = cnt[t];
    __syncthreads();
    for (int off = 1; off < NBINS; off <<= 1) {
        unsigned u = (t >= off) ? pref[t - off] : 0u;
        __syncthreads();
        pref[t] += u;
        __syncthreads();
    }
    {
        unsigned ex = pref[t] - cnt[t];
        __syncthreads();
        pref[t] = ex;
    }
    __syncthreads();

#pragma unroll
    for (int j = 0; j < 8; j++) {
        const int s = s0 + j * 1024 + t;
        const int b = (s >= VOX_PER_B) ? 1 : 0;
        const int k = bin_of(czr[j], cyr[j], b);
        const unsigned slot = pref[k] + rankr[j];
        rec[slot] = make_float4(czr[j], cyr[j], cxr[j], __uint_as_float((unsigned)s));
        binid[slot] = (unsigned short)k;
    }
    __syncthreads();

#pragma unroll
    for (int j = 0; j < 8; j++) {
        const int i = j * 1024 + t;
        const int k = binid[i];
        records[gb[k] + (unsigned)(i - (int)pref[k])] = rec[i];  // coalesced runs
    }
}

// ---- pass 4: LDS-tile gather ------------------------------------------------
__global__ __launch_bounds__(GATHER_THREADS) void gather_kernel(
    const float* __restrict__ inp,
    const float4* __restrict__ records,
    const unsigned* __restrict__ base,
    const unsigned* __restrict__ ncnt,
    float4* __restrict__ out)
{
    __shared__ float4 tile[TILE_ELEMS];          // 92160 B
    // XCD swizzle: XCD x handles bins [x*128, x*128+128) (contiguous z-slabs)
    const int k = ((blockIdx.x & 7) << 7) | (blockIdx.x >> 3);
    const int b  = k >> 9;
    const int zb = (k >> 5) & 15;
    const int yb = k & 31;
    const int t = threadIdx.x;

    const float4* bp = (const float4*)inp + ((size_t)b << 21);
    const int zlim = min(9, D - zb * 8);
    const int ylim = min(5, H - yb * 4);
    for (int i = t; i < TILE_ELEMS; i += GATHER_THREADS) {
        const int z = i / 640;                   // 640 = 5*128
        const int r = i - z * 640;
        const int y = r >> 7;
        const int x = r & 127;
        if (z < zlim && y < ylim)
            tile[i] = bp[((zb * 8 + z) << 14) | ((yb * 4 + y) << 7) | x];
    }
    __syncthreads();

    const unsigned s = base[k];
    const unsigned n = ncnt[k];
    const int zoff = zb * 8, yoff = yb * 4;
    for (unsigned i = s + t; i < s + n; i += GATHER_THREADS) {
        const float4 r = records[i];
        const float cz = r.x, cy = r.y, cx = r.z;
        const unsigned idx = __float_as_uint(r.w);

        const int fz = (int)floorf(cz);
        const int fy = (int)floorf(cy);
        const int fx = (int)floorf(cx);
        const int z1 = min(max(fz + 1, 0), D - 1);
        const int y1 = min(max(fy + 1, 0), H - 1);
        const int x1 = min(max(fx + 1, 0), W - 1);
        const int z0 = min(max(fz, 0), D - 1);
        const int y0 = min(max(fy, 0), H - 1);
        const int x0 = min(max(fx, 0), W - 1);

        const float wz0 = (float)z1 - cz, wz1 = cz - (float)z0;
        const float wy0 = (float)y1 - cy, wy1 = cy - (float)y0;
        const float wx0 = (float)x1 - cx, wx1 = cx - (float)x0;

        const int lz0 = (z0 - zoff) * 640, lz1 = (z1 - zoff) * 640;
        const int ly0 = (y0 - yoff) * 128, ly1 = (y1 - yoff) * 128;

        const float4 s000 = tile[lz0 + ly0 + x0];
        const float4 s001 = tile[lz0 + ly0 + x1];
        const float4 s010 = tile[lz0 + ly1 + x0];
        const float4 s011 = tile[lz0 + ly1 + x1];
        const float4 s100 = tile[lz1 + ly0 + x0];
        const float4 s101 = tile[lz1 + ly0 + x1];
        const float4 s110 = tile[lz1 + ly1 + x0];
        const float4 s111 = tile[lz1 + ly1 + x1];

        float4 c00 = f4_fma(wx1, s001, f4_scale(wx0, s000));
        float4 c01 = f4_fma(wx1, s011, f4_scale(wx0, s010));
        float4 c10 = f4_fma(wx1, s101, f4_scale(wx0, s100));
        float4 c11 = f4_fma(wx1, s111, f4_scale(wx0, s110));
        float4 c0 = f4_fma(wy1, c01, f4_scale(wy0, c00));
        float4 c1 = f4_fma(wy1, c11, f4_scale(wy0, c10));
        out[idx] = f4_fma(wz1, c1, f4_scale(wz0, c0));
    }
}

// ---- fallback: direct (R1) kernel ------------------------------------------
__global__ __launch_bounds__(256) void direct_kernel(const float* __restrict__ inp,
                                                     const float* __restrict__ coords,
                                                     float4* __restrict__ out) {
    const int idx = blockIdx.x * 256 + threadIdx.x;
    if (idx >= NVOX) return;
    const float cz = coords[idx * 3 + 0];
    const float cy = coords[idx * 3 + 1];
    const float cx = coords[idx * 3 + 2];
    const int b = (idx >= VOX_PER_B) ? 1 : 0;

    const int fz = (int)floorf(cz);
    const int fy = (int)floorf(cy);
    const int fx = (int)floorf(cx);
    const int z1 = min(max(fz + 1, 0), D - 1);
    const int y1 = min(max(fy + 1, 0), H - 1);
    const int x1 = min(max(fx + 1, 0), W - 1);
    const int z0 = min(max(fz, 0), D - 1);
    const int y0 = min(max(fy, 0), H - 1);
    const int x0 = min(max(fx, 0), W - 1);
    const float wz0 = (float)z1 - cz, wz1 = cz - (float)z0;
    const float wy0 = (float)y1 - cy, wy1 = cy - (float)y0;
    const float wx0 = (float)x1 - cx, wx1 = cx - (float)x0;
    const float4* bp = (const float4*)inp + ((size_t)b << 21);
    const int z0o = z0 << 14, z1o = z1 << 14;
    const int y0o = y0 << 7,  y1o = y1 << 7;
    const float4 s000 = bp[z0o | y0o | x0];
    const float4 s001 = bp[z0o | y0o | x1];
    const float4 s010 = bp[z0o | y1o | x0];
    const float4 s011 = bp[z0o | y1o | x1];
    const float4 s100 = bp[z1o | y0o | x0];
    const float4 s101 = bp[z1o | y0o | x1];
    const float4 s110 = bp[z1o | y1o | x0];
    const float4 s111 = bp[z1o | y1o | x1];
    float4 c00 = f4_fma(wx1, s001, f4_scale(wx0, s000));
    float4 c01 = f4_fma(wx1, s011, f4_scale(wx0, s010));
    float4 c10 = f4_fma(wx1, s101, f4_scale(wx0, s100));
    float4 c11 = f4_fma(wx1, s111, f4_scale(wx0, s110));
    float4 c0 = f4_fma(wy1, c01, f4_scale(wy0, c00));
    float4 c1 = f4_fma(wy1, c11, f4_scale(wy0, c10));
    out[idx] = f4_fma(wz1, c1, f4_scale(wz0, c0));
}

extern "C" void kernel_launch(void* const* d_in, const int* in_sizes, int n_in,
                              void* d_out, int out_size, void* d_ws, size_t ws_size,
                              hipStream_t stream) {
    const float* inp    = (const float*)d_in[0];
    const float* coords = (const float*)d_in[1];
    float4* out = (float4*)d_out;

    if (ws_size < WS_REQUIRED) {
        direct_kernel<<<(NVOX + 255) / 256, 256, 0, stream>>>(inp, coords, out);
        return;
    }

    char* ws = (char*)d_ws;
    unsigned* matrix  = (unsigned*)(ws + OFF_MATRIX);
    unsigned* ncnt    = (unsigned*)(ws + OFF_NCNT);
    unsigned* base    = (unsigned*)(ws + OFF_BASE);
    float4*   records = (float4*)(ws + OFF_RECORDS);

    hist_kernel   <<<NB1, 1024, 0, stream>>>(coords, matrix);
    scanA_kernel  <<<NBINS, 256, 0, stream>>>(matrix, ncnt);
    scanB_kernel  <<<1, NBINS, 0, stream>>>(ncnt, base);
    scatter_kernel<<<NB1, 1024, 0, stream>>>(coords, matrix, base, records);
    gather_kernel <<<NBINS, GATHER_THREADS, 0, stream>>>(inp, records, base, ncnt, out);
}